// Round 12
// baseline (314.063 us; speedup 1.0000x reference)
//
#include <hip/hip_runtime.h>
#include <cstdint>
#include <cstddef>

#define T_TOK 8192
#define DDIM 1024
#define FDIM 2048
#define NEXP 8

typedef _Float16 f16x8 __attribute__((ext_vector_type(8)));
typedef _Float16 f16x4 __attribute__((ext_vector_type(4)));
typedef float f32x4 __attribute__((ext_vector_type(4)));

__device__ __forceinline__ void gl_lds16(const void* g, void* s) {
  __builtin_amdgcn_global_load_lds(
      (const __attribute__((address_space(1))) void*)g,
      (__attribute__((address_space(3))) void*)s, 16, 0, 0);
}

#define WAITVM(n) asm volatile("s_waitcnt vmcnt(" #n ")" ::: "memory")
#define BARRIER()                              \
  do {                                         \
    __builtin_amdgcn_sched_barrier(0);         \
    __builtin_amdgcn_s_barrier();              \
    __builtin_amdgcn_sched_barrier(0);         \
  } while (0)

// Abramowitz-Stegun 7.1.26, |err| <= 1.5e-7
__device__ __forceinline__ float fast_erf(float x) {
  float ax = __builtin_fabsf(x);
  float t = __builtin_amdgcn_rcpf(1.0f + 0.3275911f * ax);
  float y = t * (0.254829592f +
           t * (-0.284496736f +
           t * (1.421413741f +
           t * (-1.453152027f +
           t * 1.061405429f))));
  float r = 1.0f - y * __expf(-ax * ax);
  return __builtin_copysignf(r, x);
}

// ---------------- gating (fp64 accumulate, no atomics) + fp16 convert ----
__global__ __launch_bounds__(256) void k_gate(
    const float* __restrict__ x, const float* __restrict__ gW,
    const float* __restrict__ gb, int* __restrict__ idx,
    float* __restrict__ wgt, _Float16* __restrict__ Xh) {
  int wid = threadIdx.x >> 6, lane = threadIdx.x & 63;
  int wave = blockIdx.x * 4 + wid;
  int t0 = wave * 2;

  double acc[2][NEXP];
#pragma unroll
  for (int tk = 0; tk < 2; ++tk)
#pragma unroll
    for (int e = 0; e < NEXP; ++e) acc[tk][e] = 0.0;

#pragma unroll
  for (int ch = 0; ch < 4; ++ch) {
    int dbase = ch * 256 + 4 * lane;
    const f32x4* wp = (const f32x4*)(gW + (size_t)dbase * NEXP);
    f32x4 wv[8];
#pragma unroll
    for (int i = 0; i < 8; ++i) wv[i] = wp[i];
#pragma unroll
    for (int tk = 0; tk < 2; ++tk) {
      f32x4 xv = *(const f32x4*)(x + (size_t)(t0 + tk) * DDIM + dbase);
      f16x4 h = { (_Float16)xv[0], (_Float16)xv[1], (_Float16)xv[2], (_Float16)xv[3] };
      *(f16x4*)(Xh + (size_t)(t0 + tk) * DDIM + dbase) = h;
#pragma unroll
      for (int j = 0; j < 4; ++j) {
        double xd = (double)xv[j];
#pragma unroll
        for (int e = 0; e < NEXP; ++e)
          acc[tk][e] += xd * (double)wv[2 * j + (e >> 2)][e & 3];
      }
    }
  }

#pragma unroll
  for (int off = 32; off > 0; off >>= 1) {
#pragma unroll
    for (int tk = 0; tk < 2; ++tk)
#pragma unroll
      for (int e = 0; e < NEXP; ++e)
        acc[tk][e] += __shfl_xor(acc[tk][e], off, 64);
  }
  if (lane == 0) {
#pragma unroll
    for (int tk = 0; tk < 2; ++tk) {
      double mx = -1e300; int am = 0;
#pragma unroll
      for (int e = 0; e < NEXP; ++e) {
        acc[tk][e] += (double)gb[e];
        if (acc[tk][e] > mx) { mx = acc[tk][e]; am = e; }
      }
      double s = 0.0;
#pragma unroll
      for (int e = 0; e < NEXP; ++e) s += exp(acc[tk][e] - mx);
      idx[t0 + tk] = am;
      wgt[t0 + tk] = (float)(1.0 / s);
    }
  }
}

// ---------------- routing: counts/offsets/loss + stable rank scatter ------
__global__ __launch_bounds__(1024) void k_route(
    const int* __restrict__ idx, const float* __restrict__ wgt,
    int* __restrict__ perm, int* __restrict__ counts_out,
    int* __restrict__ offs_out, float* __restrict__ loss_out) {
  __shared__ int cnt_ws[16][NEXP];
  __shared__ float sc_ws[16][NEXP];
  __shared__ int wprefix[16][NEXP];
  __shared__ int base[NEXP];

  int tid = threadIdx.x, w = tid >> 6, lane = tid & 63;

  int c_e[NEXP];
  float s_e[NEXP];
#pragma unroll
  for (int e = 0; e < NEXP; ++e) { c_e[e] = 0; s_e[e] = 0.f; }
  for (int c = 0; c < 8; ++c) {
    int t = c * 1024 + tid;
    int my = idx[t];
    float mw = wgt[t];
#pragma unroll
    for (int e = 0; e < NEXP; ++e) {
      unsigned long long m = __ballot(my == e);
      if (lane == 0) c_e[e] += (int)__popcll(m);
      s_e[e] += (my == e) ? mw : 0.f;
    }
  }
#pragma unroll
  for (int off = 32; off > 0; off >>= 1) {
#pragma unroll
    for (int e = 0; e < NEXP; ++e) s_e[e] += __shfl_xor(s_e[e], off, 64);
  }
  if (lane == 0) {
#pragma unroll
    for (int e = 0; e < NEXP; ++e) { cnt_ws[w][e] = c_e[e]; sc_ws[w][e] = s_e[e]; }
  }
  __syncthreads();
  if (tid == 0) {
    int tot[NEXP]; float sct[NEXP];
#pragma unroll
    for (int e = 0; e < NEXP; ++e) { tot[e] = 0; sct[e] = 0.f; }
    for (int ww = 0; ww < 16; ++ww)
#pragma unroll
      for (int e = 0; e < NEXP; ++e) { tot[e] += cnt_ws[ww][e]; sct[e] += sc_ws[ww][e]; }
    int off = 0; float loss = 0.f;
#pragma unroll
    for (int e = 0; e < NEXP; ++e) {
      offs_out[e] = off; counts_out[e] = tot[e];
      base[e] = off;
      off += tot[e];
      float usage = sct[e] / ((float)tot[e] + 1e-8f);
      float d = usage - (1.0f / NEXP);
      loss += d * d;
    }
    loss_out[0] = loss;
  }
  __syncthreads();

  unsigned long long lt_mask = ((unsigned long long)1 << lane) - 1ull;
  for (int c = 0; c < 8; ++c) {
    int t = c * 1024 + tid;
    int my = idx[t];
    int rank_w = 0;
    int wcnt[NEXP];
#pragma unroll
    for (int e = 0; e < NEXP; ++e) {
      unsigned long long m = __ballot(my == e);
      if (my == e) rank_w = (int)__popcll(m & lt_mask);
      wcnt[e] = (int)__popcll(m);
    }
    if (lane == 0) {
#pragma unroll
      for (int e = 0; e < NEXP; ++e) cnt_ws[w][e] = wcnt[e];
    }
    __syncthreads();
    if (tid < 128) {
      int ww = tid >> 3, e = tid & 7;
      int p = 0;
      for (int w2 = 0; w2 < 16; ++w2) if (w2 < ww) p += cnt_ws[w2][e];
      wprefix[ww][e] = p;
    }
    __syncthreads();
    int pos = base[my] + wprefix[w][my] + rank_w;
    perm[pos] = t;
    __syncthreads();
    if (tid < 8) base[tid] += wprefix[15][tid] + cnt_ws[15][tid];
    __syncthreads();
  }
}

// ---------------- transpose + fp32->fp16 convert (64x64, vectorized) -----
__global__ __launch_bounds__(256) void k_transpose_cvt(
    const float* __restrict__ src, _Float16* __restrict__ dst, int R, int C) {
  __shared__ _Float16 tile[64][72];
  int t = threadIdx.x;
  size_t base = (size_t)blockIdx.z * (size_t)R * (size_t)C;
  int c0 = blockIdx.x * 64, r0 = blockIdx.y * 64;

  int lrr = t >> 4;
  int lc4 = t & 15;
#pragma unroll
  for (int i = 0; i < 4; ++i) {
    int r = lrr + i * 16;
    float4 v = *(const float4*)(src + base + (size_t)(r0 + r) * C + c0 + lc4 * 4);
    tile[r][lc4 * 4 + 0] = (_Float16)v.x;
    tile[r][lc4 * 4 + 1] = (_Float16)v.y;
    tile[r][lc4 * 4 + 2] = (_Float16)v.z;
    tile[r][lc4 * 4 + 3] = (_Float16)v.w;
  }
  __syncthreads();

  int oc = t >> 2;
  int ch = t & 3;
#pragma unroll
  for (int i = 0; i < 2; ++i) {
    int chunk = ch + i * 4;
    f16x8 v;
#pragma unroll
    for (int j = 0; j < 8; ++j) v[j] = tile[chunk * 8 + j][oc];
    *(f16x8*)(dst + base + (size_t)(c0 + oc) * R + r0 + chunk * 8) = v;
  }
}

// ====== GEMM1 + GLU: 8-phase 256x(128+128), BK=64, 512 thr, dbuf =========
// grid: x = 16 (128-glu-col panels), y = 256 (e*32 + mi)
__global__ __launch_bounds__(512, 2) void k_gemm1_glu(
    const _Float16* __restrict__ Xh, const _Float16* __restrict__ Wt,
    const float* __restrict__ fcb, const int* __restrict__ offs,
    const int* __restrict__ counts, const int* __restrict__ perm,
    _Float16* __restrict__ G) {
  int orig = blockIdx.y * 16 + blockIdx.x;      // 0..4095
  int swz = (orig & 7) * 512 + (orig >> 3);     // bijective XCD swizzle
  int mx = swz & 15, my = swz >> 4;             // my 0..255
  int e = my >> 5;
  int m0 = (my & 31) * 256;
  int n_e = counts[e];
  if (m0 >= n_e) return;
  int seg = offs[e];
  int n0 = mx * 128;

  __shared__ __align__(16) _Float16 As[2][256][64];  // 64 KB
  __shared__ __align__(16) _Float16 Bs[2][256][64];  // 64 KB

  int tid = threadIdx.x, wid = tid >> 6, lane = tid & 63;
  int wm = wid >> 2, wn = wid & 3;

  const _Float16* We = Wt + (size_t)e * (4096ull * 1024ull);
  const float* fcbe = fcb + e * 4096;

  // ---- staging geometry: half-tile = 128 rows x 64 cols = 16 KB = 16 x 1KB
  // segments; wave w stages segments w*2, w*2+1; lane covers 16B chunk.
  // LDS[r][c] = global[r][c ^ (r&7)]  (chunk = 16B = 8 f16)
  int lrow8 = lane >> 3;            // row within 8-row segment
  int lchunk = lane & 7;
  int schunk = lchunk ^ lrow8;      // pre-swizzled source chunk (r&7 == lrow8)
  const _Float16* gA[2][2]; const _Float16* gB[2][2];
  int dstoff[2];                    // f16 units, per (l); h adds 8192
#pragma unroll
  for (int l = 0; l < 2; ++l) {
    int s = wid * 2 + l;
    dstoff[l] = s * 512 + lane * 8;
    int r = s * 8 + lrow8;          // 0..127 within half
#pragma unroll
    for (int h = 0; h < 2; ++h) {
      int growA = min(seg + m0 + h * 128 + r, T_TOK - 1);
      gA[h][l] = Xh + (size_t)perm[growA] * DDIM + schunk * 8;
      gB[h][l] = We + (size_t)(h * 2048 + n0 + r) * DDIM + schunk * 8;
    }
  }

#define ST_A(buf, h, kt)                                                   \
  do {                                                                     \
    gl_lds16(gA[h][0] + (kt) * 64, &As[(buf)][0][0] + (h)*8192 + dstoff[0]); \
    gl_lds16(gA[h][1] + (kt) * 64, &As[(buf)][0][0] + (h)*8192 + dstoff[1]); \
  } while (0)
#define ST_B(buf, h, kt)                                                   \
  do {                                                                     \
    gl_lds16(gB[h][0] + (kt) * 64, &Bs[(buf)][0][0] + (h)*8192 + dstoff[0]); \
    gl_lds16(gB[h][1] + (kt) * 64, &Bs[(buf)][0][0] + (h)*8192 + dstoff[1]); \
  } while (0)

  f32x4 acc1[8][2], acc2[8][2];
#pragma unroll
  for (int a = 0; a < 8; ++a)
#pragma unroll
    for (int b = 0; b < 2; ++b) {
      acc1[a][b] = (f32x4){0.f, 0.f, 0.f, 0.f};
      acc2[a][b] = (f32x4){0.f, 0.f, 0.f, 0.f};
    }

  int lr = lane & 15, g = lane >> 4;
  int coff0 = ((0 * 4 + g) ^ (lr & 7)) * 16;  // bytes
  int coff1 = ((1 * 4 + g) ^ (lr & 7)) * 16;

  f16x8 af[4][2], b1f[2][2], b2f[2][2];

#define RD_A(pAc, mbase)                                                   \
  do {                                                                     \
    _Pragma("unroll")                                                      \
    for (int mf = 0; mf < 4; ++mf) {                                       \
      int rb = (wm * 128 + ((mbase) + mf) * 16 + lr) * 128;                \
      af[mf][0] = *(const f16x8*)((pAc) + rb + coff0);                     \
      af[mf][1] = *(const f16x8*)((pAc) + rb + coff1);                     \
    }                                                                      \
  } while (0)
#define RD_B(pBc, bf, hofs)                                                \
  do {                                                                     \
    _Pragma("unroll")                                                      \
    for (int nf = 0; nf < 2; ++nf) {                                       \
      int rb = ((hofs) + wn * 32 + nf * 16 + lr) * 128;                    \
      bf[nf][0] = *(const f16x8*)((pBc) + rb + coff0);                     \
      bf[nf][1] = *(const f16x8*)((pBc) + rb + coff1);                     \
    }                                                                      \
  } while (0)
#define MM(accv, mbase, bf)                                                \
  do {                                                                     \
    __builtin_amdgcn_s_setprio(1);                                         \
    _Pragma("unroll")                                                      \
    for (int mf = 0; mf < 4; ++mf)                                         \
      _Pragma("unroll")                                                    \
      for (int nf = 0; nf < 2; ++nf) {                                     \
        accv[(mbase) + mf][nf] = __builtin_amdgcn_mfma_f32_16x16x32_f16(   \
            af[mf][0], bf[nf][0], accv[(mbase) + mf][nf], 0, 0, 0);        \
        accv[(mbase) + mf][nf] = __builtin_amdgcn_mfma_f32_16x16x32_f16(   \
            af[mf][1], bf[nf][1], accv[(mbase) + mf][nf], 0, 0, 0);        \
      }                                                                    \
    __builtin_amdgcn_s_setprio(0);                                         \
  } while (0)

  // prologue: stage tile 0 (order: A-top, A-bot, B1, B2)
  ST_A(0, 0, 0); ST_A(0, 1, 0); ST_B(0, 0, 0); ST_B(0, 1, 0);

  int buf = 0;
  for (int kt = 0; kt < 16; ++kt) {
    const char* pAc = (const char*)&As[buf][0][0];
    const char* pBc = (const char*)&Bs[buf][0][0];
    // ---- phase 1: stage A-top(kt+1); compute m0..3 x B1
    if (kt < 15) ST_A(buf ^ 1, 0, kt + 1);
    WAITVM(4);
    BARRIER();
    RD_A(pAc, 0);
    RD_B(pBc, b1f, 0);
    MM(acc1, 0, b1f);
    BARRIER();
    // ---- phase 2: stage A-bot(kt+1); compute m0..3 x B2
    if (kt < 15) ST_A(buf ^ 1, 1, kt + 1);
    WAITVM(4);
    BARRIER();
    RD_B(pBc, b2f, 128);
    MM(acc2, 0, b2f);
    BARRIER();
    // ---- phase 3: stage B1(kt+1); compute m4..7 x B1
    if (kt < 15) ST_B(buf ^ 1, 0, kt + 1);
    BARRIER();
    RD_A(pAc, 4);
    MM(acc1, 4, b1f);
    BARRIER();
    // ---- phase 4: stage B2(kt+1); compute m4..7 x B2
    if (kt < 15) ST_B(buf ^ 1, 1, kt + 1);
    BARRIER();
    MM(acc2, 4, b2f);
    BARRIER();
    buf ^= 1;
  }

  // ---- epilogue: GLU + store
#pragma unroll
  for (int mf = 0; mf < 8; ++mf) {
#pragma unroll
    for (int i = 0; i < 4; ++i) {
      int row = m0 + wm * 128 + mf * 16 + g * 4 + i;
      if (row >= n_e) continue;
      size_t grow = (size_t)(seg + row) * FDIM;
#pragma unroll
      for (int nf = 0; nf < 2; ++nf) {
        int col = n0 + wn * 32 + nf * 16 + lr;
        float x1 = acc1[mf][nf][i] + fcbe[col];
        float x2v = acc2[mf][nf][i] + fcbe[2048 + col];
        float gg = x1 * x2v * 0.5f * (1.0f + fast_erf(x2v * 0.70710678118654752f));
        G[grow + col] = (_Float16)gg;
      }
    }
  }
}

// ---------------- GEMM2 (128x128, BK=32, 3-buf, counted vmcnt) — R8 ------
// grid: x = 8 (n-panels of 128), y = 128 (e*16 + mi), 256 thr
__global__ __launch_bounds__(256) void k_gemm2_out(
    const _Float16* __restrict__ G, const _Float16* __restrict__ Vt,
    const float* __restrict__ ob, const int* __restrict__ offs,
    const int* __restrict__ counts, const int* __restrict__ perm,
    const float* __restrict__ wgt, float* __restrict__ out) {
  int orig = blockIdx.y * 8 + blockIdx.x;
  int swz = (orig & 7) * 128 + (orig >> 3);
  int mx = swz & 7, my = swz >> 3;
  int e = my >> 4;
  int m0 = (my & 15) * 128;
  int n_e = counts[e];
  if (m0 >= n_e) return;
  int seg = offs[e];
  int n0 = mx * 128;

  __shared__ __align__(16) _Float16 As[3][128][32];   // 24 KB
  __shared__ __align__(16) _Float16 Bs[3][128][32];   // 24 KB

  int tid = threadIdx.x, wid = tid >> 6, lane = tid & 63;
  int wm = wid >> 1, wn = wid & 1;
  const _Float16* Ve = Vt + (size_t)e * (1024ull * 2048ull);
  const float* obe = ob + e * 1024;

  int srow = tid >> 2;
  int scol = ((tid & 3) ^ ((tid >> 3) & 3)) * 8;
  const _Float16* gA[2]; const _Float16* gB[2];
#pragma unroll
  for (int s = 0; s < 2; ++s) {
    int r = min(seg + m0 + s * 64 + srow, T_TOK - 1);
    gA[s] = G + (size_t)r * FDIM + scol;
    gB[s] = Ve + (size_t)(n0 + s * 64 + srow) * FDIM + scol;
  }

  f32x4 acc[4][4];
#pragma unroll
  for (int a = 0; a < 4; ++a)
#pragma unroll
    for (int b = 0; b < 4; ++b) acc[a][b] = (f32x4){0.f, 0.f, 0.f, 0.f};

  int lr = lane & 15, g = lane >> 4;
  int aoff[4], boff[4];
#pragma unroll
  for (int mf = 0; mf < 4; ++mf) {
    int r = wm * 64 + mf * 16 + lr;
    aoff[mf] = r * 64 + ((g ^ ((r >> 1) & 3)) * 16);
  }
#pragma unroll
  for (int nf = 0; nf < 4; ++nf) {
    int r = wn * 64 + nf * 16 + lr;
    boff[nf] = r * 64 + ((g ^ ((r >> 1) & 3)) * 16);
  }

#define G2_STAGE(dA, dB, kt)                                           \
  do {                                                                 \
    int k0_ = (kt) * 32;                                               \
    gl_lds16(gA[0] + k0_, (dA) + tid * 8);                             \
    gl_lds16(gA[1] + k0_, (dA) + 2048 + tid * 8);                      \
    gl_lds16(gB[0] + k0_, (dB) + tid * 8);                             \
    gl_lds16(gB[1] + k0_, (dB) + 2048 + tid * 8);                      \
  } while (0)

#define G2_COMPUTE(pAv, pBv)                                           \
  do {                                                                 \
    const char* pA = (const char*)(pAv);                               \
    const char* pB = (const char*)(pBv);                               \
    f16x8 a[4], b[4];                                                  \
    _Pragma("unroll")                                                  \
    for (int mf = 0; mf < 4; ++mf) a[mf] = *(const f16x8*)(pA + aoff[mf]); \
    _Pragma("unroll")                                                  \
    for (int nf = 0; nf < 4; ++nf) b[nf] = *(const f16x8*)(pB + boff[nf]); \
    _Pragma("unroll")                                                  \
    for (int mf = 0; mf < 4; ++mf)                                     \
      _Pragma("unroll")                                                \
      for (int nf = 0; nf < 4; ++nf)                                   \
        acc[mf][nf] = __builtin_amdgcn_mfma_f32_16x16x32_f16(a[mf], b[nf], acc[mf][nf], 0, 0, 0); \
  } while (0)

  _Float16 *cA = &As[0][0][0], *nA = &As[1][0][0], *fA = &As[2][0][0];
  _Float16 *cB = &Bs[0][0][0], *nB = &Bs[1][0][0], *fB = &Bs[2][0][0];

  G2_STAGE(cA, cB, 0);
  G2_STAGE(nA, nB, 1);

  for (int kt = 0; kt < 64; ++kt) {
    if (kt < 62) {
      G2_STAGE(fA, fB, kt + 2);
      WAITVM(8);
    } else if (kt == 62) {
      WAITVM(4);
    } else {
      WAITVM(0);
    }
    __builtin_amdgcn_s_barrier();
    __builtin_amdgcn_sched_barrier(0);
    G2_COMPUTE(cA, cB);
    __builtin_amdgcn_s_barrier();
    _Float16* t;
    t = cA; cA = nA; nA = fA; fA = t;
    t = cB; cB = nB; nB = fB; fB = t;
  }

  int lk4 = g * 4;
#pragma unroll
  for (int mf = 0; mf < 4; ++mf) {
#pragma unroll
    for (int i = 0; i < 4; ++i) {
      int pl = m0 + wm * 64 + mf * 16 + lk4 + i;
      if (pl >= n_e) continue;
      int p = seg + pl;
      int t = perm[p];
      float wv = wgt[t];
      float* orow = out + (size_t)t * DDIM;
#pragma unroll
      for (int nf = 0; nf < 4; ++nf) {
        int col = n0 + wn * 64 + nf * 16 + lr;
        orow[col] = (acc[mf][nf][i] + obe[col]) * wv;
      }
    }
  }
}

extern "C" void kernel_launch(void* const* d_in, const int* in_sizes, int n_in,
                              void* d_out, int out_size, void* d_ws, size_t ws_size,
                              hipStream_t stream) {
  const float* x   = (const float*)d_in[0];
  const float* gW  = (const float*)d_in[1];
  const float* gb  = (const float*)d_in[2];
  const float* fcW = (const float*)d_in[3];
  const float* fcb = (const float*)d_in[4];
  const float* oW  = (const float*)d_in[5];
  const float* ob  = (const float*)d_in[6];
  float* out = (float*)d_out;

  char* p = (char*)d_ws;
  _Float16* fcWt  = (_Float16*)p; p += (size_t)NEXP * 4096 * 1024 * 2;
  _Float16* outWt = (_Float16*)p; p += (size_t)NEXP * 1024 * 2048 * 2;
  _Float16* Xh    = (_Float16*)p; p += (size_t)T_TOK * DDIM * 2;
  _Float16* G     = (_Float16*)p; p += (size_t)T_TOK * FDIM * 2;
  int*   idx     = (int*)p;   p += T_TOK * 4;
  float* wgt     = (float*)p; p += T_TOK * 4;
  int*   perm    = (int*)p;   p += T_TOK * 4;
  int*   counts  = (int*)p;   p += 64;
  int*   offs    = (int*)p;   p += 64;

  k_gate<<<T_TOK / 8, 256, 0, stream>>>(x, gW, gb, idx, wgt, Xh);
  k_route<<<1, 1024, 0, stream>>>(idx, wgt, perm, counts, offs,
                                  out + (size_t)T_TOK * DDIM);
  k_transpose_cvt<<<dim3(4096 / 64, 1024 / 64, NEXP), 256, 0, stream>>>(fcW, fcWt, 1024, 4096);
  k_transpose_cvt<<<dim3(1024 / 64, 2048 / 64, NEXP), 256, 0, stream>>>(oW, outWt, 2048, 1024);
  k_gemm1_glu<<<dim3(16, 256), 512, 0, stream>>>(Xh, fcWt, fcb, offs, counts, perm, G);
  k_gemm2_out<<<dim3(8, 128), 256, 0, stream>>>(G, outWt, ob, offs, counts, perm, wgt, out);
}

// Round 13
// 311.089 us; speedup vs baseline: 1.0096x; 1.0096x over previous
//
#include <hip/hip_runtime.h>
#include <cstdint>
#include <cstddef>

#define T_TOK 8192
#define DDIM 1024
#define FDIM 2048
#define NEXP 8

typedef _Float16 f16x8 __attribute__((ext_vector_type(8)));
typedef _Float16 f16x4 __attribute__((ext_vector_type(4)));
typedef float f32x4 __attribute__((ext_vector_type(4)));

__device__ __forceinline__ void gl_lds16(const void* g, void* s) {
  __builtin_amdgcn_global_load_lds(
      (const __attribute__((address_space(1))) void*)g,
      (__attribute__((address_space(3))) void*)s, 16, 0, 0);
}

#define WAITVM(n) asm volatile("s_waitcnt vmcnt(" #n ")" ::: "memory")

// Abramowitz-Stegun 7.1.26, |err| <= 1.5e-7
__device__ __forceinline__ float fast_erf(float x) {
  float ax = __builtin_fabsf(x);
  float t = __builtin_amdgcn_rcpf(1.0f + 0.3275911f * ax);
  float y = t * (0.254829592f +
           t * (-0.284496736f +
           t * (1.421413741f +
           t * (-1.453152027f +
           t * 1.061405429f))));
  float r = 1.0f - y * __expf(-ax * ax);
  return __builtin_copysignf(r, x);
}

// ---------------- gating (fp64 accumulate, no atomics) + fp16 convert ----
__global__ __launch_bounds__(256) void k_gate(
    const float* __restrict__ x, const float* __restrict__ gW,
    const float* __restrict__ gb, int* __restrict__ idx,
    float* __restrict__ wgt, _Float16* __restrict__ Xh) {
  int wid = threadIdx.x >> 6, lane = threadIdx.x & 63;
  int wave = blockIdx.x * 4 + wid;
  int t0 = wave * 2;

  double acc[2][NEXP];
#pragma unroll
  for (int tk = 0; tk < 2; ++tk)
#pragma unroll
    for (int e = 0; e < NEXP; ++e) acc[tk][e] = 0.0;

#pragma unroll
  for (int ch = 0; ch < 4; ++ch) {
    int dbase = ch * 256 + 4 * lane;
    const f32x4* wp = (const f32x4*)(gW + (size_t)dbase * NEXP);
    f32x4 wv[8];
#pragma unroll
    for (int i = 0; i < 8; ++i) wv[i] = wp[i];
#pragma unroll
    for (int tk = 0; tk < 2; ++tk) {
      f32x4 xv = *(const f32x4*)(x + (size_t)(t0 + tk) * DDIM + dbase);
      f16x4 h = { (_Float16)xv[0], (_Float16)xv[1], (_Float16)xv[2], (_Float16)xv[3] };
      *(f16x4*)(Xh + (size_t)(t0 + tk) * DDIM + dbase) = h;
#pragma unroll
      for (int j = 0; j < 4; ++j) {
        double xd = (double)xv[j];
#pragma unroll
        for (int e = 0; e < NEXP; ++e)
          acc[tk][e] += xd * (double)wv[2 * j + (e >> 2)][e & 3];
      }
    }
  }

#pragma unroll
  for (int off = 32; off > 0; off >>= 1) {
#pragma unroll
    for (int tk = 0; tk < 2; ++tk)
#pragma unroll
      for (int e = 0; e < NEXP; ++e)
        acc[tk][e] += __shfl_xor(acc[tk][e], off, 64);
  }
  if (lane == 0) {
#pragma unroll
    for (int tk = 0; tk < 2; ++tk) {
      double mx = -1e300; int am = 0;
#pragma unroll
      for (int e = 0; e < NEXP; ++e) {
        acc[tk][e] += (double)gb[e];
        if (acc[tk][e] > mx) { mx = acc[tk][e]; am = e; }
      }
      double s = 0.0;
#pragma unroll
      for (int e = 0; e < NEXP; ++e) s += exp(acc[tk][e] - mx);
      idx[t0 + tk] = am;
      wgt[t0 + tk] = (float)(1.0 / s);
    }
  }
}

// ---------------- routing: counts/offsets/loss + stable rank scatter ------
__global__ __launch_bounds__(1024) void k_route(
    const int* __restrict__ idx, const float* __restrict__ wgt,
    int* __restrict__ perm, int* __restrict__ counts_out,
    int* __restrict__ offs_out, float* __restrict__ loss_out) {
  __shared__ int cnt_ws[16][NEXP];
  __shared__ float sc_ws[16][NEXP];
  __shared__ int wprefix[16][NEXP];
  __shared__ int base[NEXP];

  int tid = threadIdx.x, w = tid >> 6, lane = tid & 63;

  int c_e[NEXP];
  float s_e[NEXP];
#pragma unroll
  for (int e = 0; e < NEXP; ++e) { c_e[e] = 0; s_e[e] = 0.f; }
  for (int c = 0; c < 8; ++c) {
    int t = c * 1024 + tid;
    int my = idx[t];
    float mw = wgt[t];
#pragma unroll
    for (int e = 0; e < NEXP; ++e) {
      unsigned long long m = __ballot(my == e);
      if (lane == 0) c_e[e] += (int)__popcll(m);
      s_e[e] += (my == e) ? mw : 0.f;
    }
  }
#pragma unroll
  for (int off = 32; off > 0; off >>= 1) {
#pragma unroll
    for (int e = 0; e < NEXP; ++e) s_e[e] += __shfl_xor(s_e[e], off, 64);
  }
  if (lane == 0) {
#pragma unroll
    for (int e = 0; e < NEXP; ++e) { cnt_ws[w][e] = c_e[e]; sc_ws[w][e] = s_e[e]; }
  }
  __syncthreads();
  if (tid == 0) {
    int tot[NEXP]; float sct[NEXP];
#pragma unroll
    for (int e = 0; e < NEXP; ++e) { tot[e] = 0; sct[e] = 0.f; }
    for (int ww = 0; ww < 16; ++ww)
#pragma unroll
      for (int e = 0; e < NEXP; ++e) { tot[e] += cnt_ws[ww][e]; sct[e] += sc_ws[ww][e]; }
    int off = 0; float loss = 0.f;
#pragma unroll
    for (int e = 0; e < NEXP; ++e) {
      offs_out[e] = off; counts_out[e] = tot[e];
      base[e] = off;
      off += tot[e];
      float usage = sct[e] / ((float)tot[e] + 1e-8f);
      float d = usage - (1.0f / NEXP);
      loss += d * d;
    }
    loss_out[0] = loss;
  }
  __syncthreads();

  unsigned long long lt_mask = ((unsigned long long)1 << lane) - 1ull;
  for (int c = 0; c < 8; ++c) {
    int t = c * 1024 + tid;
    int my = idx[t];
    int rank_w = 0;
    int wcnt[NEXP];
#pragma unroll
    for (int e = 0; e < NEXP; ++e) {
      unsigned long long m = __ballot(my == e);
      if (my == e) rank_w = (int)__popcll(m & lt_mask);
      wcnt[e] = (int)__popcll(m);
    }
    if (lane == 0) {
#pragma unroll
      for (int e = 0; e < NEXP; ++e) cnt_ws[w][e] = wcnt[e];
    }
    __syncthreads();
    if (tid < 128) {
      int ww = tid >> 3, e = tid & 7;
      int p = 0;
      for (int w2 = 0; w2 < 16; ++w2) if (w2 < ww) p += cnt_ws[w2][e];
      wprefix[ww][e] = p;
    }
    __syncthreads();
    int pos = base[my] + wprefix[w][my] + rank_w;
    perm[pos] = t;
    __syncthreads();
    if (tid < 8) base[tid] += wprefix[15][tid] + cnt_ws[15][tid];
    __syncthreads();
  }
}

// ---------------- transpose + fp32->fp16 convert (64x64, vectorized) -----
__global__ __launch_bounds__(256) void k_transpose_cvt(
    const float* __restrict__ src, _Float16* __restrict__ dst, int R, int C) {
  __shared__ _Float16 tile[64][72];
  int t = threadIdx.x;
  size_t base = (size_t)blockIdx.z * (size_t)R * (size_t)C;
  int c0 = blockIdx.x * 64, r0 = blockIdx.y * 64;

  int lrr = t >> 4;
  int lc4 = t & 15;
#pragma unroll
  for (int i = 0; i < 4; ++i) {
    int r = lrr + i * 16;
    float4 v = *(const float4*)(src + base + (size_t)(r0 + r) * C + c0 + lc4 * 4);
    tile[r][lc4 * 4 + 0] = (_Float16)v.x;
    tile[r][lc4 * 4 + 1] = (_Float16)v.y;
    tile[r][lc4 * 4 + 2] = (_Float16)v.z;
    tile[r][lc4 * 4 + 3] = (_Float16)v.w;
  }
  __syncthreads();

  int oc = t >> 2;
  int ch = t & 3;
#pragma unroll
  for (int i = 0; i < 2; ++i) {
    int chunk = ch + i * 4;
    f16x8 v;
#pragma unroll
    for (int j = 0; j < 8; ++j) v[j] = tile[chunk * 8 + j][oc];
    *(f16x8*)(dst + base + (size_t)(c0 + oc) * R + r0 + chunk * 8) = v;
  }
}

// ====== GEMM1 + GLU: 8-phase 256x(128+128), BK=64, 512 thr, dbuf =========
// grid: x = 16 (128-glu-col panels), y = 256 (e*32 + mi)
__global__ __launch_bounds__(512, 2) void k_gemm1_glu(
    const _Float16* __restrict__ Xh, const _Float16* __restrict__ Wt,
    const float* __restrict__ fcb, const int* __restrict__ offs,
    const int* __restrict__ counts, const int* __restrict__ perm,
    _Float16* __restrict__ G) {
  int orig = blockIdx.y * 16 + blockIdx.x;      // 0..4095
  int swz = (orig & 7) * 512 + (orig >> 3);     // bijective XCD swizzle
  int mx = swz & 15, my = swz >> 4;             // my 0..255
  int e = my >> 5;
  int m0 = (my & 31) * 256;
  int n_e = counts[e];
  if (m0 >= n_e) return;
  int seg = offs[e];
  int n0 = mx * 128;

  __shared__ __align__(16) _Float16 As[2][256][64];  // 64 KB
  __shared__ __align__(16) _Float16 Bs[2][256][64];  // 64 KB

  int tid = threadIdx.x, wid = tid >> 6, lane = tid & 63;
  int wm = wid >> 2, wn = wid & 3;

  const _Float16* We = Wt + (size_t)e * (4096ull * 1024ull);
  const float* fcbe = fcb + e * 4096;

  // staging: LDS[r][c] = global[r][c ^ (r&7)] at 16B-chunk granularity
  int lrow8 = lane >> 3;
  int lchunk = lane & 7;
  int schunk = lchunk ^ lrow8;
  const _Float16* gA[2][2]; const _Float16* gB[2][2];
  int dstoff[2];
#pragma unroll
  for (int l = 0; l < 2; ++l) {
    int s = wid * 2 + l;
    dstoff[l] = s * 512 + lane * 8;
    int r = s * 8 + lrow8;
#pragma unroll
    for (int h = 0; h < 2; ++h) {
      int growA = min(seg + m0 + h * 128 + r, T_TOK - 1);
      gA[h][l] = Xh + (size_t)perm[growA] * DDIM + schunk * 8;
      gB[h][l] = We + (size_t)(h * 2048 + n0 + r) * DDIM + schunk * 8;
    }
  }

#define ST_A(buf, h, kt)                                                   \
  do {                                                                     \
    gl_lds16(gA[h][0] + (kt) * 64, &As[(buf)][0][0] + (h)*8192 + dstoff[0]); \
    gl_lds16(gA[h][1] + (kt) * 64, &As[(buf)][0][0] + (h)*8192 + dstoff[1]); \
  } while (0)
#define ST_B(buf, h, kt)                                                   \
  do {                                                                     \
    gl_lds16(gB[h][0] + (kt) * 64, &Bs[(buf)][0][0] + (h)*8192 + dstoff[0]); \
    gl_lds16(gB[h][1] + (kt) * 64, &Bs[(buf)][0][0] + (h)*8192 + dstoff[1]); \
  } while (0)

  f32x4 acc1[8][2], acc2[8][2];
#pragma unroll
  for (int a = 0; a < 8; ++a)
#pragma unroll
    for (int b = 0; b < 2; ++b) {
      acc1[a][b] = (f32x4){0.f, 0.f, 0.f, 0.f};
      acc2[a][b] = (f32x4){0.f, 0.f, 0.f, 0.f};
    }

  int lr = lane & 15, g = lane >> 4;
  int coff0 = ((0 * 4 + g) ^ (lr & 7)) * 16;  // bytes
  int coff1 = ((1 * 4 + g) ^ (lr & 7)) * 16;

  f16x8 af[4][2], b1f[2][2], b2f[2][2];

#define RD_A(pAc, mbase)                                                   \
  do {                                                                     \
    _Pragma("unroll")                                                      \
    for (int mf = 0; mf < 4; ++mf) {                                       \
      int rb = (wm * 128 + ((mbase) + mf) * 16 + lr) * 128;                \
      af[mf][0] = *(const f16x8*)((pAc) + rb + coff0);                     \
      af[mf][1] = *(const f16x8*)((pAc) + rb + coff1);                     \
    }                                                                      \
  } while (0)
#define RD_B(pBc, bf, hofs)                                                \
  do {                                                                     \
    _Pragma("unroll")                                                      \
    for (int nf = 0; nf < 2; ++nf) {                                       \
      int rb = ((hofs) + wn * 32 + nf * 16 + lr) * 128;                    \
      bf[nf][0] = *(const f16x8*)((pBc) + rb + coff0);                     \
      bf[nf][1] = *(const f16x8*)((pBc) + rb + coff1);                     \
    }                                                                      \
  } while (0)
#define MM(accv, mbase, bf)                                                \
  do {                                                                     \
    __builtin_amdgcn_s_setprio(1);                                         \
    _Pragma("unroll")                                                      \
    for (int mf = 0; mf < 4; ++mf)                                         \
      _Pragma("unroll")                                                    \
      for (int nf = 0; nf < 2; ++nf) {                                     \
        accv[(mbase) + mf][nf] = __builtin_amdgcn_mfma_f32_16x16x32_f16(   \
            af[mf][0], bf[nf][0], accv[(mbase) + mf][nf], 0, 0, 0);        \
        accv[(mbase) + mf][nf] = __builtin_amdgcn_mfma_f32_16x16x32_f16(   \
            af[mf][1], bf[nf][1], accv[(mbase) + mf][nf], 0, 0, 0);        \
      }                                                                    \
    __builtin_amdgcn_s_setprio(0);                                         \
  } while (0)

#define BAR_IN()                               \
  do {                                         \
    __builtin_amdgcn_s_barrier();              \
    __builtin_amdgcn_sched_barrier(0);         \
  } while (0)

  // prologue: stage tile 0 (order: A-top, A-bot, B-h0, B-h1)
  ST_A(0, 0, 0); ST_A(0, 1, 0); ST_B(0, 0, 0); ST_B(0, 1, 0);

  int buf = 0;
  for (int kt = 0; kt < 15; ++kt) {
    const char* pAc = (const char*)&As[buf][0][0];
    const char* pBc = (const char*)&Bs[buf][0][0];
    // phase 1: stage A-top(kt+1); compute m0..3 x B1
    ST_A(buf ^ 1, 0, kt + 1);
    WAITVM(4);
    BAR_IN();
    RD_A(pAc, 0);
    RD_B(pBc, b1f, 0);
    MM(acc1, 0, b1f);
    __builtin_amdgcn_s_barrier();
    // phase 2: stage A-bot(kt+1); compute m0..3 x B2
    ST_A(buf ^ 1, 1, kt + 1);
    WAITVM(4);
    BAR_IN();
    RD_B(pBc, b2f, 128);
    MM(acc2, 0, b2f);
    __builtin_amdgcn_s_barrier();
    // phase 3: stage B-h0(kt+1); compute m4..7 x B1
    ST_B(buf ^ 1, 0, kt + 1);
    BAR_IN();
    RD_A(pAc, 4);
    MM(acc1, 4, b1f);
    __builtin_amdgcn_s_barrier();
    // phase 4: stage B-h1(kt+1); compute m4..7 x B2
    ST_B(buf ^ 1, 1, kt + 1);
    BAR_IN();
    MM(acc2, 4, b2f);
    __builtin_amdgcn_s_barrier();
    buf ^= 1;
  }
  // ---- peeled last tile (kt = 15): no stages; correct drain counts
  {
    const char* pAc = (const char*)&As[buf][0][0];
    const char* pBc = (const char*)&Bs[buf][0][0];
    WAITVM(2);            // A-top, A-bot, B-h0 landed
    BAR_IN();
    RD_A(pAc, 0);
    RD_B(pBc, b1f, 0);
    MM(acc1, 0, b1f);
    __builtin_amdgcn_s_barrier();
    WAITVM(0);            // B-h1 landed
    BAR_IN();
    RD_B(pBc, b2f, 128);
    MM(acc2, 0, b2f);
    RD_A(pAc, 4);
    MM(acc1, 4, b1f);
    MM(acc2, 4, b2f);
  }

  // ---- epilogue: GLU + store
#pragma unroll
  for (int mf = 0; mf < 8; ++mf) {
#pragma unroll
    for (int i = 0; i < 4; ++i) {
      int row = m0 + wm * 128 + mf * 16 + g * 4 + i;
      if (row >= n_e) continue;
      size_t grow = (size_t)(seg + row) * FDIM;
#pragma unroll
      for (int nf = 0; nf < 2; ++nf) {
        int col = n0 + wn * 32 + nf * 16 + lr;
        float x1 = acc1[mf][nf][i] + fcbe[col];
        float x2v = acc2[mf][nf][i] + fcbe[2048 + col];
        float gg = x1 * x2v * 0.5f * (1.0f + fast_erf(x2v * 0.70710678118654752f));
        G[grow + col] = (_Float16)gg;
      }
    }
  }
}

// ---------------- GEMM2 (128x128, BK=32, 3-buf, counted vmcnt) — R8 ------
// grid: x = 8 (n-panels of 128), y = 128 (e*16 + mi), 256 thr
__global__ __launch_bounds__(256) void k_gemm2_out(
    const _Float16* __restrict__ G, const _Float16* __restrict__ Vt,
    const float* __restrict__ ob, const int* __restrict__ offs,
    const int* __restrict__ counts, const int* __restrict__ perm,
    const float* __restrict__ wgt, float* __restrict__ out) {
  int orig = blockIdx.y * 8 + blockIdx.x;
  int swz = (orig & 7) * 128 + (orig >> 3);
  int mx = swz & 7, my = swz >> 3;
  int e = my >> 4;
  int m0 = (my & 15) * 128;
  int n_e = counts[e];
  if (m0 >= n_e) return;
  int seg = offs[e];
  int n0 = mx * 128;

  __shared__ __align__(16) _Float16 As[3][128][32];   // 24 KB
  __shared__ __align__(16) _Float16 Bs[3][128][32];   // 24 KB

  int tid = threadIdx.x, wid = tid >> 6, lane = tid & 63;
  int wm = wid >> 1, wn = wid & 1;
  const _Float16* Ve = Vt + (size_t)e * (1024ull * 2048ull);
  const float* obe = ob + e * 1024;

  int srow = tid >> 2;
  int scol = ((tid & 3) ^ ((tid >> 3) & 3)) * 8;
  const _Float16* gA[2]; const _Float16* gB[2];
#pragma unroll
  for (int s = 0; s < 2; ++s) {
    int r = min(seg + m0 + s * 64 + srow, T_TOK - 1);
    gA[s] = G + (size_t)r * FDIM + scol;
    gB[s] = Ve + (size_t)(n0 + s * 64 + srow) * FDIM + scol;
  }

  f32x4 acc[4][4];
#pragma unroll
  for (int a = 0; a < 4; ++a)
#pragma unroll
    for (int b = 0; b < 4; ++b) acc[a][b] = (f32x4){0.f, 0.f, 0.f, 0.f};

  int lr = lane & 15, g = lane >> 4;
  int aoff[4], boff[4];
#pragma unroll
  for (int mf = 0; mf < 4; ++mf) {
    int r = wm * 64 + mf * 16 + lr;
    aoff[mf] = r * 64 + ((g ^ ((r >> 1) & 3)) * 16);
  }
#pragma unroll
  for (int nf = 0; nf < 4; ++nf) {
    int r = wn * 64 + nf * 16 + lr;
    boff[nf] = r * 64 + ((g ^ ((r >> 1) & 3)) * 16);
  }

#define G2_STAGE(dA, dB, kt)                                           \
  do {                                                                 \
    int k0_ = (kt) * 32;                                               \
    gl_lds16(gA[0] + k0_, (dA) + tid * 8);                             \
    gl_lds16(gA[1] + k0_, (dA) + 2048 + tid * 8);                      \
    gl_lds16(gB[0] + k0_, (dB) + tid * 8);                             \
    gl_lds16(gB[1] + k0_, (dB) + 2048 + tid * 8);                      \
  } while (0)

#define G2_COMPUTE(pAv, pBv)                                           \
  do {                                                                 \
    const char* pA = (const char*)(pAv);                               \
    const char* pB = (const char*)(pBv);                               \
    f16x8 a[4], b[4];                                                  \
    _Pragma("unroll")                                                  \
    for (int mf = 0; mf < 4; ++mf) a[mf] = *(const f16x8*)(pA + aoff[mf]); \
    _Pragma("unroll")                                                  \
    for (int nf = 0; nf < 4; ++nf) b[nf] = *(const f16x8*)(pB + boff[nf]); \
    _Pragma("unroll")                                                  \
    for (int mf = 0; mf < 4; ++mf)                                     \
      _Pragma("unroll")                                                \
      for (int nf = 0; nf < 4; ++nf)                                   \
        acc[mf][nf] = __builtin_amdgcn_mfma_f32_16x16x32_f16(a[mf], b[nf], acc[mf][nf], 0, 0, 0); \
  } while (0)

  _Float16 *cA = &As[0][0][0], *nA = &As[1][0][0], *fA = &As[2][0][0];
  _Float16 *cB = &Bs[0][0][0], *nB = &Bs[1][0][0], *fB = &Bs[2][0][0];

  G2_STAGE(cA, cB, 0);
  G2_STAGE(nA, nB, 1);

  for (int kt = 0; kt < 64; ++kt) {
    if (kt < 62) {
      G2_STAGE(fA, fB, kt + 2);
      WAITVM(8);
    } else if (kt == 62) {
      WAITVM(4);
    } else {
      WAITVM(0);
    }
    __builtin_amdgcn_s_barrier();
    __builtin_amdgcn_sched_barrier(0);
    G2_COMPUTE(cA, cB);
    __builtin_amdgcn_s_barrier();
    _Float16* t;
    t = cA; cA = nA; nA = fA; fA = t;
    t = cB; cB = nB; nB = fB; fB = t;
  }

  int lk4 = g * 4;
#pragma unroll
  for (int mf = 0; mf < 4; ++mf) {
#pragma unroll
    for (int i = 0; i < 4; ++i) {
      int pl = m0 + wm * 64 + mf * 16 + lk4 + i;
      if (pl >= n_e) continue;
      int p = seg + pl;
      int t = perm[p];
      float wv = wgt[t];
      float* orow = out + (size_t)t * DDIM;
#pragma unroll
      for (int nf = 0; nf < 4; ++nf) {
        int col = n0 + wn * 64 + nf * 16 + lr;
        orow[col] = (acc[mf][nf][i] + obe[col]) * wv;
      }
    }
  }
}

extern "C" void kernel_launch(void* const* d_in, const int* in_sizes, int n_in,
                              void* d_out, int out_size, void* d_ws, size_t ws_size,
                              hipStream_t stream) {
  const float* x   = (const float*)d_in[0];
  const float* gW  = (const float*)d_in[1];
  const float* gb  = (const float*)d_in[2];
  const float* fcW = (const float*)d_in[3];
  const float* fcb = (const float*)d_in[4];
  const float* oW  = (const float*)d_in[5];
  const float* ob  = (const float*)d_in[6];
  float* out = (float*)d_out;

  char* p = (char*)d_ws;
  _Float16* fcWt  = (_Float16*)p; p += (size_t)NEXP * 4096 * 1024 * 2;
  _Float16* outWt = (_Float16*)p; p += (size_t)NEXP * 1024 * 2048 * 2;
  _Float16* Xh    = (_Float16*)p; p += (size_t)T_TOK * DDIM * 2;
  _Float16* G     = (_Float16*)p; p += (size_t)T_TOK * FDIM * 2;
  int*   idx     = (int*)p;   p += T_TOK * 4;
  float* wgt     = (float*)p; p += T_TOK * 4;
  int*   perm    = (int*)p;   p += T_TOK * 4;
  int*   counts  = (int*)p;   p += 64;
  int*   offs    = (int*)p;   p += 64;

  k_gate<<<T_TOK / 8, 256, 0, stream>>>(x, gW, gb, idx, wgt, Xh);
  k_route<<<1, 1024, 0, stream>>>(idx, wgt, perm, counts, offs,
                                  out + (size_t)T_TOK * DDIM);
  k_transpose_cvt<<<dim3(4096 / 64, 1024 / 64, NEXP), 256, 0, stream>>>(fcW, fcWt, 1024, 4096);
  k_transpose_cvt<<<dim3(1024 / 64, 2048 / 64, NEXP), 256, 0, stream>>>(oW, outWt, 2048, 1024);
  k_gemm1_glu<<<dim3(16, 256), 512, 0, stream>>>(Xh, fcWt, fcb, offs, counts, perm, G);
  k_gemm2_out<<<dim3(8, 128), 256, 0, stream>>>(G, outWt, ob, offs, counts, perm, wgt, out);
}

// Round 14
// 261.248 us; speedup vs baseline: 1.2022x; 1.1908x over previous
//
#include <hip/hip_runtime.h>
#include <cstdint>
#include <cstddef>

#define T_TOK 8192
#define DDIM 1024
#define FDIM 2048
#define NEXP 8

typedef _Float16 f16x8 __attribute__((ext_vector_type(8)));
typedef _Float16 f16x4 __attribute__((ext_vector_type(4)));
typedef float f32x4 __attribute__((ext_vector_type(4)));

__device__ __forceinline__ void gl_lds16(const void* g, void* s) {
  __builtin_amdgcn_global_load_lds(
      (const __attribute__((address_space(1))) void*)g,
      (__attribute__((address_space(3))) void*)s, 16, 0, 0);
}

#define WAITVM(n) asm volatile("s_waitcnt vmcnt(" #n ")" ::: "memory")

// Abramowitz-Stegun 7.1.26, |err| <= 1.5e-7
__device__ __forceinline__ float fast_erf(float x) {
  float ax = __builtin_fabsf(x);
  float t = __builtin_amdgcn_rcpf(1.0f + 0.3275911f * ax);
  float y = t * (0.254829592f +
           t * (-0.284496736f +
           t * (1.421413741f +
           t * (-1.453152027f +
           t * 1.061405429f))));
  float r = 1.0f - y * __expf(-ax * ax);
  return __builtin_copysignf(r, x);
}

// ============ fused prep: gate (1-in-13) + both weight transposes ========
// grid = 13312 blocks x 256:  1024 gate + 8192 fcW tiles + 4096 oW tiles
__global__ __launch_bounds__(256) void k_prep(
    const float* __restrict__ x, const float* __restrict__ gW,
    const float* __restrict__ gb, int* __restrict__ idx,
    float* __restrict__ wgt, _Float16* __restrict__ Xh,
    const float* __restrict__ fcW, _Float16* __restrict__ fcWt,
    const float* __restrict__ oW, _Float16* __restrict__ outWt) {
  __shared__ _Float16 tile[64][72];
  int bid = blockIdx.x;

  if (bid % 13 == 0) {
    // ---------------- gate block ----------------
    int gblk = bid / 13;                   // 0..1023
    int wid = threadIdx.x >> 6, lane = threadIdx.x & 63;
    int wave = gblk * 4 + wid;
    int t0 = wave * 2;

    double acc[2][NEXP];
#pragma unroll
    for (int tk = 0; tk < 2; ++tk)
#pragma unroll
      for (int e = 0; e < NEXP; ++e) acc[tk][e] = 0.0;

#pragma unroll
    for (int ch = 0; ch < 4; ++ch) {
      int dbase = ch * 256 + 4 * lane;
      const f32x4* wp = (const f32x4*)(gW + (size_t)dbase * NEXP);
      f32x4 wv[8];
#pragma unroll
      for (int i = 0; i < 8; ++i) wv[i] = wp[i];
#pragma unroll
      for (int tk = 0; tk < 2; ++tk) {
        f32x4 xv = *(const f32x4*)(x + (size_t)(t0 + tk) * DDIM + dbase);
        f16x4 h = { (_Float16)xv[0], (_Float16)xv[1], (_Float16)xv[2], (_Float16)xv[3] };
        *(f16x4*)(Xh + (size_t)(t0 + tk) * DDIM + dbase) = h;
#pragma unroll
        for (int j = 0; j < 4; ++j) {
          double xd = (double)xv[j];
#pragma unroll
          for (int e = 0; e < NEXP; ++e)
            acc[tk][e] += xd * (double)wv[2 * j + (e >> 2)][e & 3];
        }
      }
    }

#pragma unroll
    for (int off = 32; off > 0; off >>= 1) {
#pragma unroll
      for (int tk = 0; tk < 2; ++tk)
#pragma unroll
        for (int e = 0; e < NEXP; ++e)
          acc[tk][e] += __shfl_xor(acc[tk][e], off, 64);
    }
    if (lane == 0) {
#pragma unroll
      for (int tk = 0; tk < 2; ++tk) {
        double mx = -1e300; int am = 0;
#pragma unroll
        for (int e = 0; e < NEXP; ++e) {
          acc[tk][e] += (double)gb[e];
          if (acc[tk][e] > mx) { mx = acc[tk][e]; am = e; }
        }
        double s = 0.0;
#pragma unroll
        for (int e = 0; e < NEXP; ++e) s += exp(acc[tk][e] - mx);
        idx[t0 + tk] = am;
        wgt[t0 + tk] = (float)(1.0 / s);
      }
    }
    return;
  }

  // ---------------- transpose tile ----------------
  int t = bid - bid / 13 - 1;              // 0..12287
  const float* src; _Float16* dst; int R, C, r0, c0; size_t base;
  if (t < 8192) {                          // fcW: [8][1024][4096] -> [8][4096][1024]
    int z = t >> 10, tt = t & 1023;
    R = 1024; C = 4096;
    r0 = ((tt >> 6) & 15) * 64; c0 = (tt & 63) * 64;
    base = (size_t)z * (size_t)R * (size_t)C;
    src = fcW; dst = fcWt;
  } else {                                 // oW: [8][2048][1024] -> [8][1024][2048]
    int t2 = t - 8192;
    int z = t2 >> 9, tt = t2 & 511;
    R = 2048; C = 1024;
    r0 = (tt >> 4) * 64; c0 = (tt & 15) * 64;
    base = (size_t)z * (size_t)R * (size_t)C;
    src = oW; dst = outWt;
  }
  int th = threadIdx.x;
  int lrr = th >> 4, lc4 = th & 15;
#pragma unroll
  for (int i = 0; i < 4; ++i) {
    int r = lrr + i * 16;
    float4 v = *(const float4*)(src + base + (size_t)(r0 + r) * C + c0 + lc4 * 4);
    tile[r][lc4 * 4 + 0] = (_Float16)v.x;
    tile[r][lc4 * 4 + 1] = (_Float16)v.y;
    tile[r][lc4 * 4 + 2] = (_Float16)v.z;
    tile[r][lc4 * 4 + 3] = (_Float16)v.w;
  }
  __syncthreads();
  int oc = th >> 2, ch = th & 3;
#pragma unroll
  for (int i = 0; i < 2; ++i) {
    int chunk = ch + i * 4;
    f16x8 v;
#pragma unroll
    for (int j = 0; j < 8; ++j) v[j] = tile[chunk * 8 + j][oc];
    *(f16x8*)(dst + base + (size_t)(c0 + oc) * R + r0 + chunk * 8) = v;
  }
}

// ---------------- routing: counts/offsets/loss + stable rank scatter ------
__global__ __launch_bounds__(1024) void k_route(
    const int* __restrict__ idx, const float* __restrict__ wgt,
    int* __restrict__ perm, int* __restrict__ counts_out,
    int* __restrict__ offs_out, float* __restrict__ loss_out) {
  __shared__ int cnt_ws[16][NEXP];
  __shared__ float sc_ws[16][NEXP];
  __shared__ int wprefix[16][NEXP];
  __shared__ int base[NEXP];

  int tid = threadIdx.x, w = tid >> 6, lane = tid & 63;

  int c_e[NEXP];
  float s_e[NEXP];
#pragma unroll
  for (int e = 0; e < NEXP; ++e) { c_e[e] = 0; s_e[e] = 0.f; }
  for (int c = 0; c < 8; ++c) {
    int t = c * 1024 + tid;
    int my = idx[t];
    float mw = wgt[t];
#pragma unroll
    for (int e = 0; e < NEXP; ++e) {
      unsigned long long m = __ballot(my == e);
      if (lane == 0) c_e[e] += (int)__popcll(m);
      s_e[e] += (my == e) ? mw : 0.f;
    }
  }
#pragma unroll
  for (int off = 32; off > 0; off >>= 1) {
#pragma unroll
    for (int e = 0; e < NEXP; ++e) s_e[e] += __shfl_xor(s_e[e], off, 64);
  }
  if (lane == 0) {
#pragma unroll
    for (int e = 0; e < NEXP; ++e) { cnt_ws[w][e] = c_e[e]; sc_ws[w][e] = s_e[e]; }
  }
  __syncthreads();
  if (tid == 0) {
    int tot[NEXP]; float sct[NEXP];
#pragma unroll
    for (int e = 0; e < NEXP; ++e) { tot[e] = 0; sct[e] = 0.f; }
    for (int ww = 0; ww < 16; ++ww)
#pragma unroll
      for (int e = 0; e < NEXP; ++e) { tot[e] += cnt_ws[ww][e]; sct[e] += sc_ws[ww][e]; }
    int off = 0; float loss = 0.f;
#pragma unroll
    for (int e = 0; e < NEXP; ++e) {
      offs_out[e] = off; counts_out[e] = tot[e];
      base[e] = off;
      off += tot[e];
      float usage = sct[e] / ((float)tot[e] + 1e-8f);
      float d = usage - (1.0f / NEXP);
      loss += d * d;
    }
    loss_out[0] = loss;
  }
  __syncthreads();

  unsigned long long lt_mask = ((unsigned long long)1 << lane) - 1ull;
  for (int c = 0; c < 8; ++c) {
    int t = c * 1024 + tid;
    int my = idx[t];
    int rank_w = 0;
    int wcnt[NEXP];
#pragma unroll
    for (int e = 0; e < NEXP; ++e) {
      unsigned long long m = __ballot(my == e);
      if (my == e) rank_w = (int)__popcll(m & lt_mask);
      wcnt[e] = (int)__popcll(m);
    }
    if (lane == 0) {
#pragma unroll
      for (int e = 0; e < NEXP; ++e) cnt_ws[w][e] = wcnt[e];
    }
    __syncthreads();
    if (tid < 128) {
      int ww = tid >> 3, e = tid & 7;
      int p = 0;
      for (int w2 = 0; w2 < 16; ++w2) if (w2 < ww) p += cnt_ws[w2][e];
      wprefix[ww][e] = p;
    }
    __syncthreads();
    int pos = base[my] + wprefix[w][my] + rank_w;
    perm[pos] = t;
    __syncthreads();
    if (tid < 8) base[tid] += wprefix[15][tid] + cnt_ws[15][tid];
    __syncthreads();
  }
}

// ------ GEMM1 + GLU (128x(64+64), BK=32, 3-buf, counted vmcnt) — R8 ------
// grid: x = 32 (n-panels of 64), y = 128 (e*16 + mi), 256 thr
__global__ __launch_bounds__(256) void k_gemm1_glu(
    const _Float16* __restrict__ Xh, const _Float16* __restrict__ Wt,
    const float* __restrict__ fcb, const int* __restrict__ offs,
    const int* __restrict__ counts, const int* __restrict__ perm,
    _Float16* __restrict__ G) {
  // bijective XCD swizzle over nwg = 4096
  int orig = blockIdx.y * 32 + blockIdx.x;
  int swz = (orig & 7) * 512 + (orig >> 3);
  int mx = swz & 31, my = swz >> 5;
  int e = my >> 4;
  int m0 = (my & 15) * 128;
  int n_e = counts[e];
  if (m0 >= n_e) return;
  int seg = offs[e];
  int n0 = mx * 64;

  __shared__ __align__(16) _Float16 As[3][128][32];    // 24 KB
  __shared__ __align__(16) _Float16 B1s[3][64][32];    // 12 KB
  __shared__ __align__(16) _Float16 B2s[3][64][32];    // 12 KB

  int tid = threadIdx.x, wid = tid >> 6, lane = tid & 63;
  int wm = wid >> 1, wn = wid & 1;

  const _Float16* We = Wt + (size_t)e * (4096ull * 1024ull);
  const float* fcbe = fcb + e * 4096;

  int srow = tid >> 2;
  int scol = ((tid & 3) ^ ((tid >> 3) & 3)) * 8;
  const _Float16* gA[2];
#pragma unroll
  for (int s = 0; s < 2; ++s) {
    int rowp = min(seg + m0 + s * 64 + srow, T_TOK - 1);
    gA[s] = Xh + (size_t)perm[rowp] * DDIM + scol;
  }
  const _Float16* gB1 = We + (size_t)(n0 + srow) * DDIM + scol;
  const _Float16* gB2 = We + (size_t)(2048 + n0 + srow) * DDIM + scol;

  f32x4 acc1[4][2], acc2[4][2];
#pragma unroll
  for (int a = 0; a < 4; ++a)
#pragma unroll
    for (int b = 0; b < 2; ++b) {
      acc1[a][b] = (f32x4){0.f, 0.f, 0.f, 0.f};
      acc2[a][b] = (f32x4){0.f, 0.f, 0.f, 0.f};
    }

  int lr = lane & 15, g = lane >> 4;
  int aoff[4], boff[2];
#pragma unroll
  for (int mf = 0; mf < 4; ++mf) {
    int r = wm * 64 + mf * 16 + lr;
    aoff[mf] = r * 64 + ((g ^ ((r >> 1) & 3)) * 16);
  }
#pragma unroll
  for (int nf = 0; nf < 2; ++nf) {
    int r = wn * 32 + nf * 16 + lr;
    boff[nf] = r * 64 + ((g ^ ((r >> 1) & 3)) * 16);
  }

#define G1_STAGE(dA, dB1, dB2, kt)                                     \
  do {                                                                 \
    int k0_ = (kt) * 32;                                               \
    gl_lds16(gA[0] + k0_, (dA) + tid * 8);                             \
    gl_lds16(gA[1] + k0_, (dA) + 2048 + tid * 8);                      \
    gl_lds16(gB1 + k0_, (dB1) + tid * 8);                              \
    gl_lds16(gB2 + k0_, (dB2) + tid * 8);                              \
  } while (0)

#define G1_COMPUTE(pAv, pB1v, pB2v)                                    \
  do {                                                                 \
    const char* pA = (const char*)(pAv);                               \
    const char* pB1 = (const char*)(pB1v);                             \
    const char* pB2 = (const char*)(pB2v);                             \
    f16x8 a[4], b1[2], b2[2];                                          \
    _Pragma("unroll")                                                  \
    for (int mf = 0; mf < 4; ++mf) a[mf] = *(const f16x8*)(pA + aoff[mf]); \
    _Pragma("unroll")                                                  \
    for (int nf = 0; nf < 2; ++nf) {                                   \
      b1[nf] = *(const f16x8*)(pB1 + boff[nf]);                        \
      b2[nf] = *(const f16x8*)(pB2 + boff[nf]);                        \
    }                                                                  \
    _Pragma("unroll")                                                  \
    for (int mf = 0; mf < 4; ++mf)                                     \
      _Pragma("unroll")                                                \
      for (int nf = 0; nf < 2; ++nf) {                                 \
        acc1[mf][nf] = __builtin_amdgcn_mfma_f32_16x16x32_f16(a[mf], b1[nf], acc1[mf][nf], 0, 0, 0); \
        acc2[mf][nf] = __builtin_amdgcn_mfma_f32_16x16x32_f16(a[mf], b2[nf], acc2[mf][nf], 0, 0, 0); \
      }                                                                \
  } while (0)

  _Float16 *cA = &As[0][0][0], *nA = &As[1][0][0], *fA = &As[2][0][0];
  _Float16 *cB1 = &B1s[0][0][0], *nB1 = &B1s[1][0][0], *fB1 = &B1s[2][0][0];
  _Float16 *cB2 = &B2s[0][0][0], *nB2 = &B2s[1][0][0], *fB2 = &B2s[2][0][0];

  G1_STAGE(cA, cB1, cB2, 0);
  G1_STAGE(nA, nB1, nB2, 1);

  for (int kt = 0; kt < 32; ++kt) {
    if (kt < 30) {
      G1_STAGE(fA, fB1, fB2, kt + 2);
      WAITVM(8);
    } else if (kt == 30) {
      WAITVM(4);
    } else {
      WAITVM(0);
    }
    __builtin_amdgcn_s_barrier();
    __builtin_amdgcn_sched_barrier(0);
    G1_COMPUTE(cA, cB1, cB2);
    __builtin_amdgcn_s_barrier();
    _Float16* t;
    t = cA; cA = nA; nA = fA; fA = t;
    t = cB1; cB1 = nB1; nB1 = fB1; fB1 = t;
    t = cB2; cB2 = nB2; nB2 = fB2; fB2 = t;
  }

  int lk4 = g * 4;
#pragma unroll
  for (int mf = 0; mf < 4; ++mf) {
#pragma unroll
    for (int i = 0; i < 4; ++i) {
      int pl = m0 + wm * 64 + mf * 16 + lk4 + i;
      if (pl >= n_e) continue;
      size_t grow = (size_t)(seg + pl) * FDIM;
#pragma unroll
      for (int nf = 0; nf < 2; ++nf) {
        int col = n0 + wn * 32 + nf * 16 + lr;
        float x1 = acc1[mf][nf][i] + fcbe[col];
        float x2v = acc2[mf][nf][i] + fcbe[2048 + col];
        float gg = x1 * x2v * 0.5f * (1.0f + fast_erf(x2v * 0.70710678118654752f));
        G[grow + col] = (_Float16)gg;
      }
    }
  }
}

// ---------------- GEMM2 (128x128, BK=32, 3-buf, counted vmcnt) — R8 ------
// grid: x = 8 (n-panels of 128), y = 128 (e*16 + mi), 256 thr
__global__ __launch_bounds__(256) void k_gemm2_out(
    const _Float16* __restrict__ G, const _Float16* __restrict__ Vt,
    const float* __restrict__ ob, const int* __restrict__ offs,
    const int* __restrict__ counts, const int* __restrict__ perm,
    const float* __restrict__ wgt, float* __restrict__ out) {
  int orig = blockIdx.y * 8 + blockIdx.x;
  int swz = (orig & 7) * 128 + (orig >> 3);
  int mx = swz & 7, my = swz >> 3;
  int e = my >> 4;
  int m0 = (my & 15) * 128;
  int n_e = counts[e];
  if (m0 >= n_e) return;
  int seg = offs[e];
  int n0 = mx * 128;

  __shared__ __align__(16) _Float16 As[3][128][32];   // 24 KB
  __shared__ __align__(16) _Float16 Bs[3][128][32];   // 24 KB

  int tid = threadIdx.x, wid = tid >> 6, lane = tid & 63;
  int wm = wid >> 1, wn = wid & 1;
  const _Float16* Ve = Vt + (size_t)e * (1024ull * 2048ull);
  const float* obe = ob + e * 1024;

  int srow = tid >> 2;
  int scol = ((tid & 3) ^ ((tid >> 3) & 3)) * 8;
  const _Float16* gA[2]; const _Float16* gB[2];
#pragma unroll
  for (int s = 0; s < 2; ++s) {
    int r = min(seg + m0 + s * 64 + srow, T_TOK - 1);
    gA[s] = G + (size_t)r * FDIM + scol;
    gB[s] = Ve + (size_t)(n0 + s * 64 + srow) * FDIM + scol;
  }

  f32x4 acc[4][4];
#pragma unroll
  for (int a = 0; a < 4; ++a)
#pragma unroll
    for (int b = 0; b < 4; ++b) acc[a][b] = (f32x4){0.f, 0.f, 0.f, 0.f};

  int lr = lane & 15, g = lane >> 4;
  int aoff[4], boff[4];
#pragma unroll
  for (int mf = 0; mf < 4; ++mf) {
    int r = wm * 64 + mf * 16 + lr;
    aoff[mf] = r * 64 + ((g ^ ((r >> 1) & 3)) * 16);
  }
#pragma unroll
  for (int nf = 0; nf < 4; ++nf) {
    int r = wn * 64 + nf * 16 + lr;
    boff[nf] = r * 64 + ((g ^ ((r >> 1) & 3)) * 16);
  }

#define G2_STAGE(dA, dB, kt)                                           \
  do {                                                                 \
    int k0_ = (kt) * 32;                                               \
    gl_lds16(gA[0] + k0_, (dA) + tid * 8);                             \
    gl_lds16(gA[1] + k0_, (dA) + 2048 + tid * 8);                      \
    gl_lds16(gB[0] + k0_, (dB) + tid * 8);                             \
    gl_lds16(gB[1] + k0_, (dB) + 2048 + tid * 8);                      \
  } while (0)

#define G2_COMPUTE(pAv, pBv)                                           \
  do {                                                                 \
    const char* pA = (const char*)(pAv);                               \
    const char* pB = (const char*)(pBv);                               \
    f16x8 a[4], b[4];                                                  \
    _Pragma("unroll")                                                  \
    for (int mf = 0; mf < 4; ++mf) a[mf] = *(const f16x8*)(pA + aoff[mf]); \
    _Pragma("unroll")                                                  \
    for (int nf = 0; nf < 4; ++nf) b[nf] = *(const f16x8*)(pB + boff[nf]); \
    _Pragma("unroll")                                                  \
    for (int mf = 0; mf < 4; ++mf)                                     \
      _Pragma("unroll")                                                \
      for (int nf = 0; nf < 4; ++nf)                                   \
        acc[mf][nf] = __builtin_amdgcn_mfma_f32_16x16x32_f16(a[mf], b[nf], acc[mf][nf], 0, 0, 0); \
  } while (0)

  _Float16 *cA = &As[0][0][0], *nA = &As[1][0][0], *fA = &As[2][0][0];
  _Float16 *cB = &Bs[0][0][0], *nB = &Bs[1][0][0], *fB = &Bs[2][0][0];

  G2_STAGE(cA, cB, 0);
  G2_STAGE(nA, nB, 1);

  for (int kt = 0; kt < 64; ++kt) {
    if (kt < 62) {
      G2_STAGE(fA, fB, kt + 2);
      WAITVM(8);
    } else if (kt == 62) {
      WAITVM(4);
    } else {
      WAITVM(0);
    }
    __builtin_amdgcn_s_barrier();
    __builtin_amdgcn_sched_barrier(0);
    G2_COMPUTE(cA, cB);
    __builtin_amdgcn_s_barrier();
    _Float16* t;
    t = cA; cA = nA; nA = fA; fA = t;
    t = cB; cB = nB; nB = fB; fB = t;
  }

  int lk4 = g * 4;
#pragma unroll
  for (int mf = 0; mf < 4; ++mf) {
#pragma unroll
    for (int i = 0; i < 4; ++i) {
      int pl = m0 + wm * 64 + mf * 16 + lk4 + i;
      if (pl >= n_e) continue;
      int p = seg + pl;
      int t = perm[p];
      float wv = wgt[t];
      float* orow = out + (size_t)t * DDIM;
#pragma unroll
      for (int nf = 0; nf < 4; ++nf) {
        int col = n0 + wn * 64 + nf * 16 + lr;
        orow[col] = (acc[mf][nf][i] + obe[col]) * wv;
      }
    }
  }
}

extern "C" void kernel_launch(void* const* d_in, const int* in_sizes, int n_in,
                              void* d_out, int out_size, void* d_ws, size_t ws_size,
                              hipStream_t stream) {
  const float* x   = (const float*)d_in[0];
  const float* gW  = (const float*)d_in[1];
  const float* gb  = (const float*)d_in[2];
  const float* fcW = (const float*)d_in[3];
  const float* fcb = (const float*)d_in[4];
  const float* oW  = (const float*)d_in[5];
  const float* ob  = (const float*)d_in[6];
  float* out = (float*)d_out;

  char* p = (char*)d_ws;
  _Float16* fcWt  = (_Float16*)p; p += (size_t)NEXP * 4096 * 1024 * 2;
  _Float16* outWt = (_Float16*)p; p += (size_t)NEXP * 1024 * 2048 * 2;
  _Float16* Xh    = (_Float16*)p; p += (size_t)T_TOK * DDIM * 2;
  _Float16* G     = (_Float16*)p; p += (size_t)T_TOK * FDIM * 2;
  int*   idx     = (int*)p;   p += T_TOK * 4;
  float* wgt     = (float*)p; p += T_TOK * 4;
  int*   perm    = (int*)p;   p += T_TOK * 4;
  int*   counts  = (int*)p;   p += 64;
  int*   offs    = (int*)p;   p += 64;

  // fused: gate + fcW transpose + oW transpose (independent work items)
  k_prep<<<13312, 256, 0, stream>>>(x, gW, gb, idx, wgt, Xh,
                                    fcW, fcWt, oW, outWt);
  k_route<<<1, 1024, 0, stream>>>(idx, wgt, perm, counts, offs,
                                  out + (size_t)T_TOK * DDIM);
  k_gemm1_glu<<<dim3(32, 128), 256, 0, stream>>>(Xh, fcWt, fcb, offs, counts, perm, G);
  k_gemm2_out<<<dim3(8, 128), 256, 0, stream>>>(G, outWt, ob, offs, counts, perm, wgt, out);
}

// Round 15
// 257.309 us; speedup vs baseline: 1.2206x; 1.0153x over previous
//
#include <hip/hip_runtime.h>
#include <cstdint>
#include <cstddef>

#define T_TOK 8192
#define DDIM 1024
#define FDIM 2048
#define NEXP 8

typedef _Float16 f16x8 __attribute__((ext_vector_type(8)));
typedef _Float16 f16x4 __attribute__((ext_vector_type(4)));
typedef float f32x4 __attribute__((ext_vector_type(4)));

__device__ __forceinline__ void gl_lds16(const void* g, void* s) {
  __builtin_amdgcn_global_load_lds(
      (const __attribute__((address_space(1))) void*)g,
      (__attribute__((address_space(3))) void*)s, 16, 0, 0);
}

#define WAITVM(n) asm volatile("s_waitcnt vmcnt(" #n ")" ::: "memory")

// Abramowitz-Stegun 7.1.26, |err| <= 1.5e-7
__device__ __forceinline__ float fast_erf(float x) {
  float ax = __builtin_fabsf(x);
  float t = __builtin_amdgcn_rcpf(1.0f + 0.3275911f * ax);
  float y = t * (0.254829592f +
           t * (-0.284496736f +
           t * (1.421413741f +
           t * (-1.453152027f +
           t * 1.061405429f))));
  float r = 1.0f - y * __expf(-ax * ax);
  return __builtin_copysignf(r, x);
}

// ============ fused prep: gate (1-in-9) + fcW transpose ==================
// grid = 9216 blocks x 256:  1024 gate + 8192 fcW tiles
__global__ __launch_bounds__(256) void k_prep(
    const float* __restrict__ x, const float* __restrict__ gW,
    const float* __restrict__ gb, int* __restrict__ idx,
    float* __restrict__ wgt, _Float16* __restrict__ Xh,
    const float* __restrict__ fcW, _Float16* __restrict__ fcWt) {
  __shared__ _Float16 tile[64][72];
  int bid = blockIdx.x;

  if (bid % 9 == 0) {
    // ---------------- gate block ----------------
    int gblk = bid / 9;                    // 0..1023
    int wid = threadIdx.x >> 6, lane = threadIdx.x & 63;
    int wave = gblk * 4 + wid;
    int t0 = wave * 2;

    double acc[2][NEXP];
#pragma unroll
    for (int tk = 0; tk < 2; ++tk)
#pragma unroll
      for (int e = 0; e < NEXP; ++e) acc[tk][e] = 0.0;

#pragma unroll
    for (int ch = 0; ch < 4; ++ch) {
      int dbase = ch * 256 + 4 * lane;
      const f32x4* wp = (const f32x4*)(gW + (size_t)dbase * NEXP);
      f32x4 wv[8];
#pragma unroll
      for (int i = 0; i < 8; ++i) wv[i] = wp[i];
#pragma unroll
      for (int tk = 0; tk < 2; ++tk) {
        f32x4 xv = *(const f32x4*)(x + (size_t)(t0 + tk) * DDIM + dbase);
        f16x4 h = { (_Float16)xv[0], (_Float16)xv[1], (_Float16)xv[2], (_Float16)xv[3] };
        *(f16x4*)(Xh + (size_t)(t0 + tk) * DDIM + dbase) = h;
#pragma unroll
        for (int j = 0; j < 4; ++j) {
          double xd = (double)xv[j];
#pragma unroll
          for (int e = 0; e < NEXP; ++e)
            acc[tk][e] += xd * (double)wv[2 * j + (e >> 2)][e & 3];
        }
      }
    }

#pragma unroll
    for (int off = 32; off > 0; off >>= 1) {
#pragma unroll
      for (int tk = 0; tk < 2; ++tk)
#pragma unroll
        for (int e = 0; e < NEXP; ++e)
          acc[tk][e] += __shfl_xor(acc[tk][e], off, 64);
    }
    if (lane == 0) {
#pragma unroll
      for (int tk = 0; tk < 2; ++tk) {
        double mx = -1e300; int am = 0;
#pragma unroll
        for (int e = 0; e < NEXP; ++e) {
          acc[tk][e] += (double)gb[e];
          if (acc[tk][e] > mx) { mx = acc[tk][e]; am = e; }
        }
        double s = 0.0;
#pragma unroll
        for (int e = 0; e < NEXP; ++e) s += exp(acc[tk][e] - mx);
        idx[t0 + tk] = am;
        wgt[t0 + tk] = (float)(1.0 / s);
      }
    }
    return;
  }

  // ---------------- fcW transpose tile: [8][1024][4096] -> [8][4096][1024]
  int t = bid - bid / 9 - 1;               // 0..8191
  int z = t >> 10, tt = t & 1023;
  const int R = 1024, C = 4096;
  int r0 = ((tt >> 6) & 15) * 64, c0 = (tt & 63) * 64;
  size_t base = (size_t)z * (size_t)R * (size_t)C;
  const float* src = fcW;
  _Float16* dst = fcWt;

  int th = threadIdx.x;
  int lrr = th >> 4, lc4 = th & 15;
#pragma unroll
  for (int i = 0; i < 4; ++i) {
    int r = lrr + i * 16;
    float4 v = *(const float4*)(src + base + (size_t)(r0 + r) * C + c0 + lc4 * 4);
    tile[r][lc4 * 4 + 0] = (_Float16)v.x;
    tile[r][lc4 * 4 + 1] = (_Float16)v.y;
    tile[r][lc4 * 4 + 2] = (_Float16)v.z;
    tile[r][lc4 * 4 + 3] = (_Float16)v.w;
  }
  __syncthreads();
  int oc = th >> 2, ch = th & 3;
#pragma unroll
  for (int i = 0; i < 2; ++i) {
    int chunk = ch + i * 4;
    f16x8 v;
#pragma unroll
    for (int j = 0; j < 8; ++j) v[j] = tile[chunk * 8 + j][oc];
    *(f16x8*)(dst + base + (size_t)(c0 + oc) * R + r0 + chunk * 8) = v;
  }
}

// ---------------- routing: counts/offsets/loss + stable rank scatter ------
__global__ __launch_bounds__(1024) void k_route(
    const int* __restrict__ idx, const float* __restrict__ wgt,
    int* __restrict__ perm, int* __restrict__ counts_out,
    int* __restrict__ offs_out, float* __restrict__ loss_out) {
  __shared__ int cnt_ws[16][NEXP];
  __shared__ float sc_ws[16][NEXP];
  __shared__ int wprefix[16][NEXP];
  __shared__ int base[NEXP];

  int tid = threadIdx.x, w = tid >> 6, lane = tid & 63;

  int c_e[NEXP];
  float s_e[NEXP];
#pragma unroll
  for (int e = 0; e < NEXP; ++e) { c_e[e] = 0; s_e[e] = 0.f; }
  for (int c = 0; c < 8; ++c) {
    int t = c * 1024 + tid;
    int my = idx[t];
    float mw = wgt[t];
#pragma unroll
    for (int e = 0; e < NEXP; ++e) {
      unsigned long long m = __ballot(my == e);
      if (lane == 0) c_e[e] += (int)__popcll(m);
      s_e[e] += (my == e) ? mw : 0.f;
    }
  }
#pragma unroll
  for (int off = 32; off > 0; off >>= 1) {
#pragma unroll
    for (int e = 0; e < NEXP; ++e) s_e[e] += __shfl_xor(s_e[e], off, 64);
  }
  if (lane == 0) {
#pragma unroll
    for (int e = 0; e < NEXP; ++e) { cnt_ws[w][e] = c_e[e]; sc_ws[w][e] = s_e[e]; }
  }
  __syncthreads();
  if (tid == 0) {
    int tot[NEXP]; float sct[NEXP];
#pragma unroll
    for (int e = 0; e < NEXP; ++e) { tot[e] = 0; sct[e] = 0.f; }
    for (int ww = 0; ww < 16; ++ww)
#pragma unroll
      for (int e = 0; e < NEXP; ++e) { tot[e] += cnt_ws[ww][e]; sct[e] += sc_ws[ww][e]; }
    int off = 0; float loss = 0.f;
#pragma unroll
    for (int e = 0; e < NEXP; ++e) {
      offs_out[e] = off; counts_out[e] = tot[e];
      base[e] = off;
      off += tot[e];
      float usage = sct[e] / ((float)tot[e] + 1e-8f);
      float d = usage - (1.0f / NEXP);
      loss += d * d;
    }
    loss_out[0] = loss;
  }
  __syncthreads();

  unsigned long long lt_mask = ((unsigned long long)1 << lane) - 1ull;
  for (int c = 0; c < 8; ++c) {
    int t = c * 1024 + tid;
    int my = idx[t];
    int rank_w = 0;
    int wcnt[NEXP];
#pragma unroll
    for (int e = 0; e < NEXP; ++e) {
      unsigned long long m = __ballot(my == e);
      if (my == e) rank_w = (int)__popcll(m & lt_mask);
      wcnt[e] = (int)__popcll(m);
    }
    if (lane == 0) {
#pragma unroll
      for (int e = 0; e < NEXP; ++e) cnt_ws[w][e] = wcnt[e];
    }
    __syncthreads();
    if (tid < 128) {
      int ww = tid >> 3, e = tid & 7;
      int p = 0;
      for (int w2 = 0; w2 < 16; ++w2) if (w2 < ww) p += cnt_ws[w2][e];
      wprefix[ww][e] = p;
    }
    __syncthreads();
    int pos = base[my] + wprefix[w][my] + rank_w;
    perm[pos] = t;
    __syncthreads();
    if (tid < 8) base[tid] += wprefix[15][tid] + cnt_ws[15][tid];
    __syncthreads();
  }
}

// ------ GEMM1 + GLU (128x(64+64), BK=32, 3-buf, counted vmcnt) -----------
// grid: x = 32, y = 0..127 GEMM (e*16 + mi); y = 128..255 oW-transpose tiles
__global__ __launch_bounds__(256) void k_gemm1_glu(
    const _Float16* __restrict__ Xh, const _Float16* __restrict__ Wt,
    const float* __restrict__ fcb, const int* __restrict__ offs,
    const int* __restrict__ counts, const int* __restrict__ perm,
    _Float16* __restrict__ G,
    const float* __restrict__ oW, _Float16* __restrict__ outWt) {
  __shared__ __align__(16) _Float16 As[3][128][32];    // 24 KB
  __shared__ __align__(16) _Float16 B1s[3][64][32];    // 12 KB
  __shared__ __align__(16) _Float16 B2s[3][64][32];    // 12 KB

  if (blockIdx.y >= 128) {
    // -------- oW transpose tile: [8][2048][1024] -> [8][1024][2048] ------
    // reuse As as scratch: tile[64][72] = 9216 f16 <= 12288
    _Float16* tl = &As[0][0][0];
    int t2 = (blockIdx.y - 128) * 32 + blockIdx.x;   // 0..4095
    int z = t2 >> 9, tt = t2 & 511;
    const int R = 2048, C = 1024;
    int r0 = (tt >> 4) * 64, c0 = (tt & 15) * 64;
    size_t base = (size_t)z * (size_t)R * (size_t)C;

    int th = threadIdx.x;
    int lrr = th >> 4, lc4 = th & 15;
#pragma unroll
    for (int i = 0; i < 4; ++i) {
      int r = lrr + i * 16;
      float4 v = *(const float4*)(oW + base + (size_t)(r0 + r) * C + c0 + lc4 * 4);
      tl[r * 72 + lc4 * 4 + 0] = (_Float16)v.x;
      tl[r * 72 + lc4 * 4 + 1] = (_Float16)v.y;
      tl[r * 72 + lc4 * 4 + 2] = (_Float16)v.z;
      tl[r * 72 + lc4 * 4 + 3] = (_Float16)v.w;
    }
    __syncthreads();
    int oc = th >> 2, ch = th & 3;
#pragma unroll
    for (int i = 0; i < 2; ++i) {
      int chunk = ch + i * 4;
      f16x8 v;
#pragma unroll
      for (int j = 0; j < 8; ++j) v[j] = tl[(chunk * 8 + j) * 72 + oc];
      *(f16x8*)(outWt + base + (size_t)(c0 + oc) * R + r0 + chunk * 8) = v;
    }
    return;
  }

  // bijective XCD swizzle over the GEMM sub-grid (nwg = 4096)
  int orig = blockIdx.y * 32 + blockIdx.x;
  int swz = (orig & 7) * 512 + (orig >> 3);
  int mx = swz & 31, my = swz >> 5;
  int e = my >> 4;
  int m0 = (my & 15) * 128;
  int n_e = counts[e];
  if (m0 >= n_e) return;
  int seg = offs[e];
  int n0 = mx * 64;

  int tid = threadIdx.x, wid = tid >> 6, lane = tid & 63;
  int wm = wid >> 1, wn = wid & 1;

  const _Float16* We = Wt + (size_t)e * (4096ull * 1024ull);
  const float* fcbe = fcb + e * 4096;

  int srow = tid >> 2;
  int scol = ((tid & 3) ^ ((tid >> 3) & 3)) * 8;
  const _Float16* gA[2];
#pragma unroll
  for (int s = 0; s < 2; ++s) {
    int rowp = min(seg + m0 + s * 64 + srow, T_TOK - 1);
    gA[s] = Xh + (size_t)perm[rowp] * DDIM + scol;
  }
  const _Float16* gB1 = We + (size_t)(n0 + srow) * DDIM + scol;
  const _Float16* gB2 = We + (size_t)(2048 + n0 + srow) * DDIM + scol;

  f32x4 acc1[4][2], acc2[4][2];
#pragma unroll
  for (int a = 0; a < 4; ++a)
#pragma unroll
    for (int b = 0; b < 2; ++b) {
      acc1[a][b] = (f32x4){0.f, 0.f, 0.f, 0.f};
      acc2[a][b] = (f32x4){0.f, 0.f, 0.f, 0.f};
    }

  int lr = lane & 15, g = lane >> 4;
  int aoff[4], boff[2];
#pragma unroll
  for (int mf = 0; mf < 4; ++mf) {
    int r = wm * 64 + mf * 16 + lr;
    aoff[mf] = r * 64 + ((g ^ ((r >> 1) & 3)) * 16);
  }
#pragma unroll
  for (int nf = 0; nf < 2; ++nf) {
    int r = wn * 32 + nf * 16 + lr;
    boff[nf] = r * 64 + ((g ^ ((r >> 1) & 3)) * 16);
  }

#define G1_STAGE(dA, dB1, dB2, kt)                                     \
  do {                                                                 \
    int k0_ = (kt) * 32;                                               \
    gl_lds16(gA[0] + k0_, (dA) + tid * 8);                             \
    gl_lds16(gA[1] + k0_, (dA) + 2048 + tid * 8);                      \
    gl_lds16(gB1 + k0_, (dB1) + tid * 8);                              \
    gl_lds16(gB2 + k0_, (dB2) + tid * 8);                              \
  } while (0)

#define G1_COMPUTE(pAv, pB1v, pB2v)                                    \
  do {                                                                 \
    const char* pA = (const char*)(pAv);                               \
    const char* pB1 = (const char*)(pB1v);                             \
    const char* pB2 = (const char*)(pB2v);                             \
    f16x8 a[4], b1[2], b2[2];                                          \
    _Pragma("unroll")                                                  \
    for (int mf = 0; mf < 4; ++mf) a[mf] = *(const f16x8*)(pA + aoff[mf]); \
    _Pragma("unroll")                                                  \
    for (int nf = 0; nf < 2; ++nf) {                                   \
      b1[nf] = *(const f16x8*)(pB1 + boff[nf]);                        \
      b2[nf] = *(const f16x8*)(pB2 + boff[nf]);                        \
    }                                                                  \
    _Pragma("unroll")                                                  \
    for (int mf = 0; mf < 4; ++mf)                                     \
      _Pragma("unroll")                                                \
      for (int nf = 0; nf < 2; ++nf) {                                 \
        acc1[mf][nf] = __builtin_amdgcn_mfma_f32_16x16x32_f16(a[mf], b1[nf], acc1[mf][nf], 0, 0, 0); \
        acc2[mf][nf] = __builtin_amdgcn_mfma_f32_16x16x32_f16(a[mf], b2[nf], acc2[mf][nf], 0, 0, 0); \
      }                                                                \
  } while (0)

  _Float16 *cA = &As[0][0][0], *nA = &As[1][0][0], *fA = &As[2][0][0];
  _Float16 *cB1 = &B1s[0][0][0], *nB1 = &B1s[1][0][0], *fB1 = &B1s[2][0][0];
  _Float16 *cB2 = &B2s[0][0][0], *nB2 = &B2s[1][0][0], *fB2 = &B2s[2][0][0];

  G1_STAGE(cA, cB1, cB2, 0);
  G1_STAGE(nA, nB1, nB2, 1);

  for (int kt = 0; kt < 32; ++kt) {
    if (kt < 30) {
      G1_STAGE(fA, fB1, fB2, kt + 2);
      WAITVM(8);
    } else if (kt == 30) {
      WAITVM(4);
    } else {
      WAITVM(0);
    }
    __builtin_amdgcn_s_barrier();
    __builtin_amdgcn_sched_barrier(0);
    G1_COMPUTE(cA, cB1, cB2);
    __builtin_amdgcn_s_barrier();
    _Float16* t;
    t = cA; cA = nA; nA = fA; fA = t;
    t = cB1; cB1 = nB1; nB1 = fB1; fB1 = t;
    t = cB2; cB2 = nB2; nB2 = fB2; fB2 = t;
  }

  int lk4 = g * 4;
#pragma unroll
  for (int mf = 0; mf < 4; ++mf) {
#pragma unroll
    for (int i = 0; i < 4; ++i) {
      int pl = m0 + wm * 64 + mf * 16 + lk4 + i;
      if (pl >= n_e) continue;
      size_t grow = (size_t)(seg + pl) * FDIM;
#pragma unroll
      for (int nf = 0; nf < 2; ++nf) {
        int col = n0 + wn * 32 + nf * 16 + lr;
        float x1 = acc1[mf][nf][i] + fcbe[col];
        float x2v = acc2[mf][nf][i] + fcbe[2048 + col];
        float gg = x1 * x2v * 0.5f * (1.0f + fast_erf(x2v * 0.70710678118654752f));
        G[grow + col] = (_Float16)gg;
      }
    }
  }
}

// ---------------- GEMM2 (128x128, BK=32, 3-buf, counted vmcnt) — R8 ------
// grid: x = 8 (n-panels of 128), y = 128 (e*16 + mi), 256 thr
__global__ __launch_bounds__(256) void k_gemm2_out(
    const _Float16* __restrict__ G, const _Float16* __restrict__ Vt,
    const float* __restrict__ ob, const int* __restrict__ offs,
    const int* __restrict__ counts, const int* __restrict__ perm,
    const float* __restrict__ wgt, float* __restrict__ out) {
  int orig = blockIdx.y * 8 + blockIdx.x;
  int swz = (orig & 7) * 128 + (orig >> 3);
  int mx = swz & 7, my = swz >> 3;
  int e = my >> 4;
  int m0 = (my & 15) * 128;
  int n_e = counts[e];
  if (m0 >= n_e) return;
  int seg = offs[e];
  int n0 = mx * 128;

  __shared__ __align__(16) _Float16 As[3][128][32];   // 24 KB
  __shared__ __align__(16) _Float16 Bs[3][128][32];   // 24 KB

  int tid = threadIdx.x, wid = tid >> 6, lane = tid & 63;
  int wm = wid >> 1, wn = wid & 1;
  const _Float16* Ve = Vt + (size_t)e * (1024ull * 2048ull);
  const float* obe = ob + e * 1024;

  int srow = tid >> 2;
  int scol = ((tid & 3) ^ ((tid >> 3) & 3)) * 8;
  const _Float16* gA[2]; const _Float16* gB[2];
#pragma unroll
  for (int s = 0; s < 2; ++s) {
    int r = min(seg + m0 + s * 64 + srow, T_TOK - 1);
    gA[s] = G + (size_t)r * FDIM + scol;
    gB[s] = Ve + (size_t)(n0 + s * 64 + srow) * FDIM + scol;
  }

  f32x4 acc[4][4];
#pragma unroll
  for (int a = 0; a < 4; ++a)
#pragma unroll
    for (int b = 0; b < 4; ++b) acc[a][b] = (f32x4){0.f, 0.f, 0.f, 0.f};

  int lr = lane & 15, g = lane >> 4;
  int aoff[4], boff[4];
#pragma unroll
  for (int mf = 0; mf < 4; ++mf) {
    int r = wm * 64 + mf * 16 + lr;
    aoff[mf] = r * 64 + ((g ^ ((r >> 1) & 3)) * 16);
  }
#pragma unroll
  for (int nf = 0; nf < 4; ++nf) {
    int r = wn * 64 + nf * 16 + lr;
    boff[nf] = r * 64 + ((g ^ ((r >> 1) & 3)) * 16);
  }

#define G2_STAGE(dA, dB, kt)                                           \
  do {                                                                 \
    int k0_ = (kt) * 32;                                               \
    gl_lds16(gA[0] + k0_, (dA) + tid * 8);                             \
    gl_lds16(gA[1] + k0_, (dA) + 2048 + tid * 8);                      \
    gl_lds16(gB[0] + k0_, (dB) + tid * 8);                             \
    gl_lds16(gB[1] + k0_, (dB) + 2048 + tid * 8);                      \
  } while (0)

#define G2_COMPUTE(pAv, pBv)                                           \
  do {                                                                 \
    const char* pA = (const char*)(pAv);                               \
    const char* pB = (const char*)(pBv);                               \
    f16x8 a[4], b[4];                                                  \
    _Pragma("unroll")                                                  \
    for (int mf = 0; mf < 4; ++mf) a[mf] = *(const f16x8*)(pA + aoff[mf]); \
    _Pragma("unroll")                                                  \
    for (int nf = 0; nf < 4; ++nf) b[nf] = *(const f16x8*)(pB + boff[nf]); \
    _Pragma("unroll")                                                  \
    for (int mf = 0; mf < 4; ++mf)                                     \
      _Pragma("unroll")                                                \
      for (int nf = 0; nf < 4; ++nf)                                   \
        acc[mf][nf] = __builtin_amdgcn_mfma_f32_16x16x32_f16(a[mf], b[nf], acc[mf][nf], 0, 0, 0); \
  } while (0)

  _Float16 *cA = &As[0][0][0], *nA = &As[1][0][0], *fA = &As[2][0][0];
  _Float16 *cB = &Bs[0][0][0], *nB = &Bs[1][0][0], *fB = &Bs[2][0][0];

  G2_STAGE(cA, cB, 0);
  G2_STAGE(nA, nB, 1);

  for (int kt = 0; kt < 64; ++kt) {
    if (kt < 62) {
      G2_STAGE(fA, fB, kt + 2);
      WAITVM(8);
    } else if (kt == 62) {
      WAITVM(4);
    } else {
      WAITVM(0);
    }
    __builtin_amdgcn_s_barrier();
    __builtin_amdgcn_sched_barrier(0);
    G2_COMPUTE(cA, cB);
    __builtin_amdgcn_s_barrier();
    _Float16* t;
    t = cA; cA = nA; nA = fA; fA = t;
    t = cB; cB = nB; nB = fB; fB = t;
  }

  int lk4 = g * 4;
#pragma unroll
  for (int mf = 0; mf < 4; ++mf) {
#pragma unroll
    for (int i = 0; i < 4; ++i) {
      int pl = m0 + wm * 64 + mf * 16 + lk4 + i;
      if (pl >= n_e) continue;
      int p = seg + pl;
      int t = perm[p];
      float wv = wgt[t];
      float* orow = out + (size_t)t * DDIM;
#pragma unroll
      for (int nf = 0; nf < 4; ++nf) {
        int col = n0 + wn * 64 + nf * 16 + lr;
        orow[col] = (acc[mf][nf][i] + obe[col]) * wv;
      }
    }
  }
}

extern "C" void kernel_launch(void* const* d_in, const int* in_sizes, int n_in,
                              void* d_out, int out_size, void* d_ws, size_t ws_size,
                              hipStream_t stream) {
  const float* x   = (const float*)d_in[0];
  const float* gW  = (const float*)d_in[1];
  const float* gb  = (const float*)d_in[2];
  const float* fcW = (const float*)d_in[3];
  const float* fcb = (const float*)d_in[4];
  const float* oW  = (const float*)d_in[5];
  const float* ob  = (const float*)d_in[6];
  float* out = (float*)d_out;

  char* p = (char*)d_ws;
  _Float16* fcWt  = (_Float16*)p; p += (size_t)NEXP * 4096 * 1024 * 2;
  _Float16* outWt = (_Float16*)p; p += (size_t)NEXP * 1024 * 2048 * 2;
  _Float16* Xh    = (_Float16*)p; p += (size_t)T_TOK * DDIM * 2;
  _Float16* G     = (_Float16*)p; p += (size_t)T_TOK * FDIM * 2;
  int*   idx     = (int*)p;   p += T_TOK * 4;
  float* wgt     = (float*)p; p += T_TOK * 4;
  int*   perm    = (int*)p;   p += T_TOK * 4;
  int*   counts  = (int*)p;   p += 64;
  int*   offs    = (int*)p;   p += 64;

  // prep: gate + fcW transpose (oW transpose moved into gemm1's grid tail)
  k_prep<<<9216, 256, 0, stream>>>(x, gW, gb, idx, wgt, Xh, fcW, fcWt);
  k_route<<<1, 1024, 0, stream>>>(idx, wgt, perm, counts, offs,
                                  out + (size_t)T_TOK * DDIM);
  k_gemm1_glu<<<dim3(32, 256), 256, 0, stream>>>(Xh, fcWt, fcb, offs, counts,
                                                 perm, G, oW, outWt);
  k_gemm2_out<<<dim3(8, 128), 256, 0, stream>>>(G, outWt, ob, offs, counts, perm, wgt, out);
}